// Round 2
// baseline (328.912 us; speedup 1.0000x reference)
//
#include <hip/hip_runtime.h>

#define BN   64
#define CIN  512
#define COUT 512
#define HW   784
#define NT   128      /* o-tile */
#define MT   112
#define BK   64
#define NKB  (CIN / BK)   /* 8 k-blocks */

typedef __attribute__((ext_vector_type(8))) short short8;
typedef __attribute__((ext_vector_type(4))) float f32x4;

__device__ __forceinline__ unsigned short f2bf(float f) {
    union { float f; unsigned int u; } v; v.f = f;
    unsigned int r = v.u + 0x7fffu + ((v.u >> 16) & 1u);   // RNE
    return (unsigned short)(r >> 16);
}

__device__ __forceinline__ uint2 pack4(float a, float b, float c, float d) {
    uint2 r;
    r.x = (unsigned int)f2bf(a) | ((unsigned int)f2bf(b) << 16);
    r.y = (unsigned int)f2bf(c) | ((unsigned int)f2bf(d) << 16);
    return r;
}

// ---------------- Pass 0: W f32 -> bf16 (tiny, 1.5 MB traffic) ----------------
__global__ __launch_bounds__(256)
void p0_wcvt(const float* __restrict__ W, unsigned short* __restrict__ Wb)
{
    int gi = blockIdx.x * 256 + threadIdx.x;        // 32768 granules of 8
    const float* p = W + (size_t)gi * 8;
    float4 a = *(const float4*)p;
    float4 c = *(const float4*)(p + 4);
    uint2 lo = pack4(a.x, a.y, a.z, a.w);
    uint2 hi = pack4(c.x, c.y, c.z, c.w);
    uint4 v; v.x = lo.x; v.y = lo.y; v.z = hi.x; v.w = hi.y;
    *(uint4*)(Wb + (size_t)gi * 8) = v;
}

// ---------------- Fused: p2_gemm geometry + in-kernel shift+cvt staging ----------------
// 256 threads / 4 waves, wave tile 32o x 112hw (acc 56 VGPR). o-tile 128, grid 1792.
// x staged per block (4x redundant across ot); XCD-pair swizzle makes repeats L2 hits.
struct XR { float4 v0, v1, v2, v3; float e0, e1, e2, e3; };

__global__ __launch_bounds__(256, 3)
void p_fused(const float* __restrict__ x, const unsigned short* __restrict__ Wb,
             const float* __restrict__ gamma, const float* __restrict__ beta,
             const float* __restrict__ rmean, const float* __restrict__ rvar,
             float* __restrict__ out)
{
    __shared__ unsigned short sX[2][MT * BK];   // 2 x 14336 B, xor-granule swizzled

    const int t  = threadIdx.x;
    // XCD-pairing swizzle: 4 o-tile sharers of one x-slab at ids {base,+8,+16,+24}
    const int id   = blockIdx.x;                 // 0..1791
    const int ot   = (id >> 3) & 3;
    const int pair = ((id >> 5) << 3) | (id & 7);   // 0..447
    const int mt   = pair % 7;
    const int b    = pair / 7;
    const int o_base  = ot * NT;
    const int hw_base = mt * MT;
    const int lane = t & 63, wv = t >> 6, m16 = lane & 15, q = lane >> 4;
    const float* xb = x + (size_t)b * CIN * HW;

    // staging: each thread owns up to two 4c x 4hw micro-tiles (items A, B)
    const int cq  = t & 15;                     // c-quad (same for both items)
    const int mqA = t >> 4;                     // 0..15  (always active)
    const int mqB = mqA + 16;                   // 16..31 (active < 28 -> t < 192)
    const bool actB = (mqB < 28);
    const int hwA = hw_base + mqA * 4;
    const int hA  = hwA / 28,  wA = hwA - hA * 28;
    const int hwB = hw_base + mqB * 4;
    const int hB  = hwB / 28,  wB = hwB - hB * 28;

    XR ra, rb;

    auto loadx = [&](int kk, int hw, int h, int w0, XR& r) {
        const int g = kk >> 1;                  // shift group, block-uniform
        const float* src = xb + (size_t)(kk * BK + cq * 4) * HW;
        if (g < 2) {
            int shw = hw + (g == 0 ? 28 : HW - 28);
            if (shw >= HW) shw -= HW;
            r.v0 = *(const float4*)(src + 0 * HW + shw);
            r.v1 = *(const float4*)(src + 1 * HW + shw);
            r.v2 = *(const float4*)(src + 2 * HW + shw);
            r.v3 = *(const float4*)(src + 3 * HW + shw);
        } else {
            const int base = h * 28;
            const int wx = (g == 2) ? ((w0 + 4 < 28) ? (w0 + 4) : 0)
                                    : ((w0 == 0) ? 27 : (w0 - 1));
            const float* r0 = src + 0 * HW + base;
            const float* r1 = src + 1 * HW + base;
            const float* r2 = src + 2 * HW + base;
            const float* r3 = src + 3 * HW + base;
            r.v0 = *(const float4*)(r0 + w0);  r.e0 = r0[wx];
            r.v1 = *(const float4*)(r1 + w0);  r.e1 = r1[wx];
            r.v2 = *(const float4*)(r2 + w0);  r.e2 = r2[wx];
            r.v3 = *(const float4*)(r3 + w0);  r.e3 = r3[wx];
        }
    };

    auto packst = [&](int kk, int mq, const XR& r, unsigned short* buf) {
        const int g = kk >> 1;
        float4 r0 = r.v0, r1 = r.v1, r2 = r.v2, r3 = r.v3;
        if (g == 2) {           // roll -1 along W: out[w] = x[w+1]
            r0 = make_float4(r.v0.y, r.v0.z, r.v0.w, r.e0);
            r1 = make_float4(r.v1.y, r.v1.z, r.v1.w, r.e1);
            r2 = make_float4(r.v2.y, r.v2.z, r.v2.w, r.e2);
            r3 = make_float4(r.v3.y, r.v3.z, r.v3.w, r.e3);
        } else if (g == 3) {    // roll +1 along W: out[w] = x[w-1]
            r0 = make_float4(r.e0, r.v0.x, r.v0.y, r.v0.z);
            r1 = make_float4(r.e1, r.v1.x, r.v1.y, r.v1.z);
            r2 = make_float4(r.e2, r.v2.x, r.v2.y, r.v2.z);
            r3 = make_float4(r.e3, r.v3.x, r.v3.y, r.v3.z);
        }
        // transpose 4c x 4hw -> per-hw uint2 of 4 consecutive c (bf16)
        uint2 u0 = pack4(r0.x, r1.x, r2.x, r3.x);
        uint2 u1 = pack4(r0.y, r1.y, r2.y, r3.y);
        uint2 u2 = pack4(r0.z, r1.z, r2.z, r3.z);
        uint2 u3 = pack4(r0.w, r1.w, r2.w, r3.w);
        const int m0 = mq * 4;
        const int gr = cq >> 1, hf4 = (cq & 1) * 4;
        *(uint2*)(&buf[(m0 + 0) * BK + ((gr ^ ((m0 + 0) & 7)) * 8) + hf4]) = u0;
        *(uint2*)(&buf[(m0 + 1) * BK + ((gr ^ ((m0 + 1) & 7)) * 8) + hf4]) = u1;
        *(uint2*)(&buf[(m0 + 2) * BK + ((gr ^ ((m0 + 2) & 7)) * 8) + hf4]) = u2;
        *(uint2*)(&buf[(m0 + 3) * BK + ((gr ^ ((m0 + 3) & 7)) * 8) + hf4]) = u3;
    };

    // per-wave W row pointers (bo = 0,1), k offset in ushorts
    const unsigned short* wr0 = Wb + (size_t)(o_base + wv * 32 + m16) * CIN + q * 8;
    const unsigned short* wr1 = wr0 + 16 * CIN;

    short8 wc[2][2], wn[2][2];   // [ks][bo] current / next
#define LOADW(DST, KK)                                  \
    {   const int ko = (KK) * 64;                       \
        DST[0][0] = *(const short8*)(wr0 + ko);         \
        DST[0][1] = *(const short8*)(wr1 + ko);         \
        DST[1][0] = *(const short8*)(wr0 + ko + 32);    \
        DST[1][1] = *(const short8*)(wr1 + ko + 32);    \
    }

    f32x4 acc[2][7];
    #pragma unroll
    for (int i = 0; i < 2; ++i)
        #pragma unroll
        for (int j = 0; j < 7; ++j)
            acc[i][j] = (f32x4){0.f, 0.f, 0.f, 0.f};

#define COMPUTE(XS, WF)                                                          \
    {                                                                            \
        const unsigned short* xs = (XS);                                         \
        _Pragma("unroll")                                                        \
        for (int ks = 0; ks < 2; ++ks) {                                         \
            _Pragma("unroll")                                                    \
            for (int bm = 0; bm < 7; ++bm) {                                     \
                int m  = bm * 16 + m16;                                          \
                int sl = (ks * 4 + q) ^ (m & 7);                                 \
                short8 bf = *(const short8*)(&xs[m * BK + sl * 8]);              \
                acc[0][bm] = __builtin_amdgcn_mfma_f32_16x16x32_bf16(WF[ks][0], bf, acc[0][bm], 0, 0, 0); \
                acc[1][bm] = __builtin_amdgcn_mfma_f32_16x16x32_bf16(WF[ks][1], bf, acc[1][bm], 0, 0, 0); \
            }                                                                    \
        }                                                                        \
    }

    // prologue: stage k-block 0
    loadx(0, hwA, hA, wA, ra);
    if (actB) loadx(0, hwB, hB, wB, rb);
    LOADW(wc, 0);
    packst(0, mqA, ra, sX[0]);
    if (actB) packst(0, mqB, rb, sX[0]);
    __syncthreads();

    #pragma unroll 1
    for (int kp = 0; kp < 4; ++kp) {
        {   // even kk = 2kp: compute buf0, prefetch kk+1 -> buf1 + wn
            const int kn = 2 * kp + 1;
            loadx(kn, hwA, hA, wA, ra);
            if (actB) loadx(kn, hwB, hB, wB, rb);
            LOADW(wn, kn);
            COMPUTE(sX[0], wc);
            packst(kn, mqA, ra, sX[1]);
            if (actB) packst(kn, mqB, rb, sX[1]);
            __syncthreads();
        }
        {   // odd kk = 2kp+1: compute buf1, prefetch kk+2 -> buf0 + wc
            const int kn = 2 * kp + 2;
            if (kn < NKB) {
                loadx(kn, hwA, hA, wA, ra);
                if (actB) loadx(kn, hwB, hB, wB, rb);
                LOADW(wc, kn);
            }
            COMPUTE(sX[1], wn);
            if (kn < NKB) {
                packst(kn, mqA, ra, sX[0]);
                if (actB) packst(kn, mqB, rb, sX[0]);
            }
            __syncthreads();
        }
    }
#undef COMPUTE
#undef LOADW

    // epilogue: BN fold + ReLU + nontemporal store
    float scl[2][4], shf[2][4];
    #pragma unroll
    for (int bo = 0; bo < 2; ++bo)
        #pragma unroll
        for (int r = 0; r < 4; ++r) {
            int o = o_base + wv * 32 + bo * 16 + q * 4 + r;
            float sc = gamma[o] * rsqrtf(rvar[o] + 1e-5f);
            scl[bo][r] = sc;
            shf[bo][r] = beta[o] - rmean[o] * sc;
        }
    float* outb = out + (size_t)b * COUT * HW;
    #pragma unroll
    for (int bo = 0; bo < 2; ++bo) {
        #pragma unroll
        for (int r = 0; r < 4; ++r) {
            int o = o_base + wv * 32 + bo * 16 + q * 4 + r;
            float* orow = outb + (size_t)o * HW + hw_base + m16;
            #pragma unroll
            for (int bm = 0; bm < 7; ++bm) {
                float y = acc[bo][bm][r] * scl[bo][r] + shf[bo][r];
                y = fmaxf(y, 0.f);
                __builtin_nontemporal_store(y, orow + bm * 16);
            }
        }
    }
}

// ---------------- Fallback (ws too small): round-1 single-pass ----------------
#define SW_STRIDE 72
#define SX_STRIDE 64
__global__ __launch_bounds__(256, 2)
void shiftconv_fallback(const float* __restrict__ x, const float* __restrict__ Wf,
                        const float* __restrict__ gamma, const float* __restrict__ beta,
                        const float* __restrict__ rmean, const float* __restrict__ rvar,
                        float* __restrict__ out)
{
    __shared__ unsigned short sW[NT * SW_STRIDE];
    __shared__ unsigned short sX[MT * SX_STRIDE];
    const int t = threadIdx.x;
    const int ot = blockIdx.x, mt = blockIdx.y, b = blockIdx.z;
    const int o_base = ot * NT, hw_base = mt * MT;
    const float* xb = x + (size_t)b * CIN * HW;
    const int lane = t & 63, wv = t >> 6, m16 = lane & 15, q = lane >> 4;
    f32x4 acc[2][7];
    #pragma unroll
    for (int i = 0; i < 2; ++i)
        #pragma unroll
        for (int j = 0; j < 7; ++j) acc[i][j] = (f32x4){0.f, 0.f, 0.f, 0.f};
    #pragma unroll
    for (int kk = 0; kk < CIN / BK; ++kk) {
        const int k0 = kk * BK;
        const int g = k0 >> 7;
        #pragma unroll
        for (int e0 = 0; e0 < 2; ++e0) {
            int e = t + e0 * 256;
            if (e < (BK / 4) * (MT / 4)) {
                int cq = e / 28, mq = e - cq * 28;
                int hw = hw_base + mq * 4;
                const float* src = xb + (size_t)(k0 + cq * 4) * HW;
                float4 v0, v1, v2, v3;
                if (g < 2) {
                    int shw = hw + (g == 0 ? 28 : HW - 28);
                    if (shw >= HW) shw -= HW;
                    v0 = *(const float4*)(src + 0 * HW + shw);
                    v1 = *(const float4*)(src + 1 * HW + shw);
                    v2 = *(const float4*)(src + 2 * HW + shw);
                    v3 = *(const float4*)(src + 3 * HW + shw);
                } else {
                    int h = hw / 28, w0 = hw - h * 28, base = h * 28;
                    #pragma unroll
                    for (int j = 0; j < 4; ++j) {
                        const float* row = src + j * HW + base;
                        float4 a = *(const float4*)(row + w0);
                        float4 r;
                        if (g == 2) {
                            float ex = row[(w0 + 4 < 28) ? (w0 + 4) : 0];
                            r.x = a.y; r.y = a.z; r.z = a.w; r.w = ex;
                        } else {
                            float ex = row[(w0 == 0) ? 27 : (w0 - 1)];
                            r.x = ex; r.y = a.x; r.z = a.y; r.w = a.z;
                        }
                        if (j == 0) v0 = r; else if (j == 1) v1 = r;
                        else if (j == 2) v2 = r; else v3 = r;
                    }
                }
                int m0 = mq * 4;
                { int p = (cq + 5 * (m0 + 0)) & 15;
                  *(uint2*)(&sX[(m0 + 0) * SX_STRIDE + p * 4]) = pack4(v0.x, v1.x, v2.x, v3.x); }
                { int p = (cq + 5 * (m0 + 1)) & 15;
                  *(uint2*)(&sX[(m0 + 1) * SX_STRIDE + p * 4]) = pack4(v0.y, v1.y, v2.y, v3.y); }
                { int p = (cq + 5 * (m0 + 2)) & 15;
                  *(uint2*)(&sX[(m0 + 2) * SX_STRIDE + p * 4]) = pack4(v0.z, v1.z, v2.z, v3.z); }
                { int p = (cq + 5 * (m0 + 3)) & 15;
                  *(uint2*)(&sX[(m0 + 3) * SX_STRIDE + p * 4]) = pack4(v0.w, v1.w, v2.w, v3.w); }
            }
        }
        #pragma unroll
        for (int i = 0; i < 4; ++i) {
            int e = t + i * 256;
            int ol = e >> 3, kg = (e & 7) * 8;
            const float* wr = Wf + (size_t)(o_base + ol) * CIN + k0 + kg;
            float4 a = *(const float4*)(wr);
            float4 c = *(const float4*)(wr + 4);
            uint2 lo = pack4(a.x, a.y, a.z, a.w);
            uint2 hi = pack4(c.x, c.y, c.z, c.w);
            uint4 v; v.x = lo.x; v.y = lo.y; v.z = hi.x; v.w = hi.y;
            *(uint4*)(&sW[ol * SW_STRIDE + kg]) = v;
        }
        __syncthreads();
        #pragma unroll
        for (int ks = 0; ks < BK; ks += 32) {
            short8 afrag[2];
            #pragma unroll
            for (int bo = 0; bo < 2; ++bo) {
                int row = wv * 32 + bo * 16 + m16;
                afrag[bo] = *(const short8*)(&sW[row * SW_STRIDE + ks + q * 8]);
            }
            #pragma unroll
            for (int bm = 0; bm < 7; ++bm) {
                int m = bm * 16 + m16;
                int g0 = (ks >> 2) + 2 * q;
                int p0 = (g0 + 5 * m) & 15;
                int p1 = (g0 + 1 + 5 * m) & 15;
                uint2 lo = *(const uint2*)(&sX[m * SX_STRIDE + p0 * 4]);
                uint2 hi = *(const uint2*)(&sX[m * SX_STRIDE + p1 * 4]);
                union { uint2 u2[2]; short8 s; } fb;
                fb.u2[0] = lo; fb.u2[1] = hi;
                acc[0][bm] = __builtin_amdgcn_mfma_f32_16x16x32_bf16(afrag[0], fb.s, acc[0][bm], 0, 0, 0);
                acc[1][bm] = __builtin_amdgcn_mfma_f32_16x16x32_bf16(afrag[1], fb.s, acc[1][bm], 0, 0, 0);
            }
        }
        __syncthreads();
    }
    float scl[2][4], shf[2][4];
    #pragma unroll
    for (int bo = 0; bo < 2; ++bo)
        #pragma unroll
        for (int r = 0; r < 4; ++r) {
            int o = o_base + wv * 32 + bo * 16 + q * 4 + r;
            float sc = gamma[o] * rsqrtf(rvar[o] + 1e-5f);
            scl[bo][r] = sc;
            shf[bo][r] = beta[o] - rmean[o] * sc;
        }
    float* outb = out + (size_t)b * COUT * HW;
    #pragma unroll
    for (int bo = 0; bo < 2; ++bo)
        #pragma unroll
        for (int r = 0; r < 4; ++r) {
            int o = o_base + wv * 32 + bo * 16 + q * 4 + r;
            float* orow = outb + (size_t)o * HW + hw_base + m16;
            #pragma unroll
            for (int bm = 0; bm < 7; ++bm) {
                float y = acc[bo][bm][r] * scl[bo][r] + shf[bo][r];
                y = fmaxf(y, 0.f);
                __builtin_nontemporal_store(y, orow + bm * 16);
            }
        }
}

extern "C" void kernel_launch(void* const* d_in, const int* in_sizes, int n_in,
                              void* d_out, int out_size, void* d_ws, size_t ws_size,
                              hipStream_t stream)
{
    const float* x     = (const float*)d_in[0];
    const float* W     = (const float*)d_in[1];
    const float* gamma = (const float*)d_in[2];
    const float* beta  = (const float*)d_in[3];
    const float* rmean = (const float*)d_in[4];
    const float* rvar  = (const float*)d_in[5];
    float* out = (float*)d_out;

    const size_t wb_bytes = (size_t)COUT * CIN * 2;                 // 512 KB
    if (ws_size >= wb_bytes) {
        unsigned short* Wb = (unsigned short*)d_ws;
        p0_wcvt<<<dim3(128), dim3(256), 0, stream>>>(W, Wb);
        p_fused<<<dim3(1792), dim3(256), 0, stream>>>(x, Wb, gamma, beta, rmean, rvar, out);
    } else {
        dim3 grid(COUT / NT, HW / MT, BN);
        shiftconv_fallback<<<grid, 256, 0, stream>>>(x, W, gamma, beta, rmean, rvar, out);
    }
}

// Round 3
// 235.310 us; speedup vs baseline: 1.3978x; 1.3978x over previous
//
#include <hip/hip_runtime.h>

#define BN   64
#define CIN  512
#define COUT 512
#define HW   784
#define NT   128      /* fallback o-tile */
#define MT   112
#define BK   64
#define NKB  (CIN / BK)   /* 8 k-blocks */

typedef __attribute__((ext_vector_type(8))) short short8;
typedef __attribute__((ext_vector_type(4))) float f32x4;

__device__ __forceinline__ unsigned short f2bf(float f) {
    union { float f; unsigned int u; } v; v.f = f;
    unsigned int r = v.u + 0x7fffu + ((v.u >> 16) & 1u);   // RNE
    return (unsigned short)(r >> 16);
}

__device__ __forceinline__ uint2 pack4(float a, float b, float c, float d) {
    uint2 r;
    r.x = (unsigned int)f2bf(a) | ((unsigned int)f2bf(b) << 16);
    r.y = (unsigned int)f2bf(c) | ((unsigned int)f2bf(d) << 16);
    return r;
}

// ---------------- Pass 0: W f32 -> bf16 (tiny, 1.5 MB traffic) ----------------
__global__ __launch_bounds__(256)
void p0_wcvt(const float* __restrict__ W, unsigned short* __restrict__ Wb)
{
    int gi = blockIdx.x * 256 + threadIdx.x;        // 32768 granules of 8
    const float* p = W + (size_t)gi * 8;
    float4 a = *(const float4*)p;
    float4 c = *(const float4*)(p + 4);
    uint2 lo = pack4(a.x, a.y, a.z, a.w);
    uint2 hi = pack4(c.x, c.y, c.z, c.w);
    uint4 v; v.x = lo.x; v.y = lo.y; v.z = hi.x; v.w = hi.y;
    *(uint4*)(Wb + (size_t)gi * 8) = v;
}

// ---------------- Fused: full-COUT, 8 resident k-buffers, 2 barriers total ----------------
// 512 threads / 8 waves; wave = 64o x 112hw (acc[4][7]). x staged exactly once.
// Pipeline: stage k0-3 (no barriers) | bar | compute k0-3 while staging k4-7
// (loads issued 2 phases ahead) | bar | compute k4-7. LDS = 8 x 14336 = 112 KiB.
struct XR { float4 v0, v1, v2, v3; float e0, e1, e2, e3; };

__global__ __launch_bounds__(512, 2)
void p_fused(const float* __restrict__ x, const unsigned short* __restrict__ Wb,
             const float* __restrict__ gamma, const float* __restrict__ beta,
             const float* __restrict__ rmean, const float* __restrict__ rvar,
             float* __restrict__ out)
{
    __shared__ unsigned short sX[NKB][MT * BK];   // 114688 B, xor-granule swizzled

    const int t  = threadIdx.x;
    const int id = blockIdx.x;                  // 0..447
    const int mt = id % 7;
    const int b  = id / 7;
    const int hw_base = mt * MT;
    const int lane = t & 63, wv = t >> 6, m16 = lane & 15, q = lane >> 4;
    const float* xb = x + (size_t)b * CIN * HW;

    // staging mapping: one 4c x 4hw micro-tile per thread; wave 7 idle during staging
    const int cq = t & 15;                      // c-quad within BK
    const int mq = t >> 4;                      // hw-quad; active when < 28
    const bool act = (mq < 28);                 // wave-uniform (t < 448)
    const int hw = hw_base + mq * 4;
    const int h  = hw / 28;
    const int w0 = hw - h * 28;

    XR ra, rb;

    auto loadx = [&](int kk, XR& r) {
        const int g = kk >> 1;                  // shift group, block-uniform
        const float* src = xb + (size_t)(kk * BK + cq * 4) * HW;
        if (g < 2) {
            int shw = hw + (g == 0 ? 28 : HW - 28);
            if (shw >= HW) shw -= HW;
            r.v0 = *(const float4*)(src + 0 * HW + shw);
            r.v1 = *(const float4*)(src + 1 * HW + shw);
            r.v2 = *(const float4*)(src + 2 * HW + shw);
            r.v3 = *(const float4*)(src + 3 * HW + shw);
        } else {
            const int base = h * 28;
            const int wx = (g == 2) ? ((w0 + 4 < 28) ? (w0 + 4) : 0)
                                    : ((w0 == 0) ? 27 : (w0 - 1));
            const float* r0 = src + 0 * HW + base;
            const float* r1 = src + 1 * HW + base;
            const float* r2 = src + 2 * HW + base;
            const float* r3 = src + 3 * HW + base;
            r.v0 = *(const float4*)(r0 + w0);  r.e0 = r0[wx];
            r.v1 = *(const float4*)(r1 + w0);  r.e1 = r1[wx];
            r.v2 = *(const float4*)(r2 + w0);  r.e2 = r2[wx];
            r.v3 = *(const float4*)(r3 + w0);  r.e3 = r3[wx];
        }
    };

    auto packst = [&](int kk, const XR& r, unsigned short* buf) {
        const int g = kk >> 1;
        float4 r0 = r.v0, r1 = r.v1, r2 = r.v2, r3 = r.v3;
        if (g == 2) {           // roll -1 along W: out[w] = x[w+1]
            r0 = make_float4(r.v0.y, r.v0.z, r.v0.w, r.e0);
            r1 = make_float4(r.v1.y, r.v1.z, r.v1.w, r.e1);
            r2 = make_float4(r.v2.y, r.v2.z, r.v2.w, r.e2);
            r3 = make_float4(r.v3.y, r.v3.z, r.v3.w, r.e3);
        } else if (g == 3) {    // roll +1 along W: out[w] = x[w-1]
            r0 = make_float4(r.e0, r.v0.x, r.v0.y, r.v0.z);
            r1 = make_float4(r.e1, r.v1.x, r.v1.y, r.v1.z);
            r2 = make_float4(r.e2, r.v2.x, r.v2.y, r.v2.z);
            r3 = make_float4(r.e3, r.v3.x, r.v3.y, r.v3.z);
        }
        // transpose 4c x 4hw -> per-hw uint2 of 4 consecutive c (bf16)
        uint2 u0 = pack4(r0.x, r1.x, r2.x, r3.x);
        uint2 u1 = pack4(r0.y, r1.y, r2.y, r3.y);
        uint2 u2 = pack4(r0.z, r1.z, r2.z, r3.z);
        uint2 u3 = pack4(r0.w, r1.w, r2.w, r3.w);
        const int m0 = mq * 4;
        const int gr = cq >> 1, hf4 = (cq & 1) * 4;
        *(uint2*)(&buf[(m0 + 0) * BK + ((gr ^ ((m0 + 0) & 7)) * 8) + hf4]) = u0;
        *(uint2*)(&buf[(m0 + 1) * BK + ((gr ^ ((m0 + 1) & 7)) * 8) + hf4]) = u1;
        *(uint2*)(&buf[(m0 + 2) * BK + ((gr ^ ((m0 + 2) & 7)) * 8) + hf4]) = u2;
        *(uint2*)(&buf[(m0 + 3) * BK + ((gr ^ ((m0 + 3) & 7)) * 8) + hf4]) = u3;
    };

    // W row pointers: 4 o-frags of 16 per wave, k-offset q*8
    const unsigned short* wr0 = Wb + (size_t)(wv * 64 + m16) * CIN + q * 8;
    const unsigned short* wr1 = wr0 + 16 * CIN;
    const unsigned short* wr2 = wr0 + 32 * CIN;
    const unsigned short* wr3 = wr0 + 48 * CIN;

    f32x4 acc[4][7];
    #pragma unroll
    for (int i = 0; i < 4; ++i)
        #pragma unroll
        for (int j = 0; j < 7; ++j)
            acc[i][j] = (f32x4){0.f, 0.f, 0.f, 0.f};

#define MFMA16(A, B, C) __builtin_amdgcn_mfma_f32_16x16x32_bf16((A), (B), (C), 0, 0, 0)
#define PHASE(KK, XS)                                                            \
    {                                                                            \
        const int ko = (KK) * 64;                                                \
        short8 wf0 = *(const short8*)(wr0 + ko);                                 \
        short8 wf1 = *(const short8*)(wr1 + ko);                                 \
        short8 wf2 = *(const short8*)(wr2 + ko);                                 \
        short8 wf3 = *(const short8*)(wr3 + ko);                                 \
        short8 wg0 = *(const short8*)(wr0 + ko + 32);                            \
        short8 wg1 = *(const short8*)(wr1 + ko + 32);                            \
        short8 wg2 = *(const short8*)(wr2 + ko + 32);                            \
        short8 wg3 = *(const short8*)(wr3 + ko + 32);                            \
        const unsigned short* xs = (XS);                                         \
        _Pragma("unroll")                                                        \
        for (int bm = 0; bm < 7; ++bm) {                                         \
            int m   = bm * 16 + m16;                                             \
            int sl0 = q ^ (m & 7);                                               \
            int sl1 = (4 + q) ^ (m & 7);                                         \
            short8 bf0 = *(const short8*)(&xs[m * BK + sl0 * 8]);                \
            short8 bf1 = *(const short8*)(&xs[m * BK + sl1 * 8]);                \
            acc[0][bm] = MFMA16(wf0, bf0, acc[0][bm]);                           \
            acc[1][bm] = MFMA16(wf1, bf0, acc[1][bm]);                           \
            acc[2][bm] = MFMA16(wf2, bf0, acc[2][bm]);                           \
            acc[3][bm] = MFMA16(wf3, bf0, acc[3][bm]);                           \
            acc[0][bm] = MFMA16(wg0, bf1, acc[0][bm]);                           \
            acc[1][bm] = MFMA16(wg1, bf1, acc[1][bm]);                           \
            acc[2][bm] = MFMA16(wg2, bf1, acc[2][bm]);                           \
            acc[3][bm] = MFMA16(wg3, bf1, acc[3][bm]);                           \
        }                                                                        \
    }

    // ---- stage k0..3, 2-deep pipelined, no intra barriers ----
    if (act) {
        loadx(0, ra);
        loadx(1, rb);
        packst(0, ra, sX[0]);
        loadx(2, ra);
        packst(1, rb, sX[1]);
        loadx(3, rb);
        packst(2, ra, sX[2]);
        packst(3, rb, sX[3]);
    }
    __syncthreads();

    // ---- compute k0..3 while staging k4..7 (loads 2 phases ahead) ----
    if (act) loadx(4, ra);
    {
        if (act) loadx(5, rb);
        PHASE(0, sX[0]);
        if (act) packst(4, ra, sX[4]);
    }
    {
        if (act) loadx(6, ra);
        PHASE(1, sX[1]);
        if (act) packst(5, rb, sX[5]);
    }
    {
        if (act) loadx(7, rb);
        PHASE(2, sX[2]);
        if (act) packst(6, ra, sX[6]);
    }
    {
        PHASE(3, sX[3]);
        if (act) packst(7, rb, sX[7]);
    }
    __syncthreads();

    // ---- compute k4..7: pure LDS + L2 W reads, no staging ----
    PHASE(4, sX[4]);
    PHASE(5, sX[5]);
    PHASE(6, sX[6]);
    PHASE(7, sX[7]);
#undef PHASE
#undef MFMA16

    // epilogue: BN fold + ReLU + nontemporal store
    float scl[4][4], shf[4][4];
    #pragma unroll
    for (int bo = 0; bo < 4; ++bo)
        #pragma unroll
        for (int r = 0; r < 4; ++r) {
            int o = wv * 64 + bo * 16 + q * 4 + r;
            float sc = gamma[o] * rsqrtf(rvar[o] + 1e-5f);
            scl[bo][r] = sc;
            shf[bo][r] = beta[o] - rmean[o] * sc;
        }
    float* outb = out + (size_t)b * COUT * HW;
    #pragma unroll
    for (int bo = 0; bo < 4; ++bo) {
        #pragma unroll
        for (int r = 0; r < 4; ++r) {
            int o = wv * 64 + bo * 16 + q * 4 + r;
            float* orow = outb + (size_t)o * HW + hw_base + m16;
            #pragma unroll
            for (int bm = 0; bm < 7; ++bm) {
                float y = acc[bo][bm][r] * scl[bo][r] + shf[bo][r];
                y = fmaxf(y, 0.f);
                __builtin_nontemporal_store(y, orow + bm * 16);
            }
        }
    }
}

// ---------------- Fallback (ws too small): round-1 single-pass ----------------
#define SW_STRIDE 72
#define SX_STRIDE 64
__global__ __launch_bounds__(256, 2)
void shiftconv_fallback(const float* __restrict__ x, const float* __restrict__ Wf,
                        const float* __restrict__ gamma, const float* __restrict__ beta,
                        const float* __restrict__ rmean, const float* __restrict__ rvar,
                        float* __restrict__ out)
{
    __shared__ unsigned short sW[NT * SW_STRIDE];
    __shared__ unsigned short sX[MT * SX_STRIDE];
    const int t = threadIdx.x;
    const int ot = blockIdx.x, mt = blockIdx.y, b = blockIdx.z;
    const int o_base = ot * NT, hw_base = mt * MT;
    const float* xb = x + (size_t)b * CIN * HW;
    const int lane = t & 63, wv = t >> 6, m16 = lane & 15, q = lane >> 4;
    f32x4 acc[2][7];
    #pragma unroll
    for (int i = 0; i < 2; ++i)
        #pragma unroll
        for (int j = 0; j < 7; ++j) acc[i][j] = (f32x4){0.f, 0.f, 0.f, 0.f};
    #pragma unroll
    for (int kk = 0; kk < CIN / BK; ++kk) {
        const int k0 = kk * BK;
        const int g = k0 >> 7;
        #pragma unroll
        for (int e0 = 0; e0 < 2; ++e0) {
            int e = t + e0 * 256;
            if (e < (BK / 4) * (MT / 4)) {
                int cq = e / 28, mq = e - cq * 28;
                int hw = hw_base + mq * 4;
                const float* src = xb + (size_t)(k0 + cq * 4) * HW;
                float4 v0, v1, v2, v3;
                if (g < 2) {
                    int shw = hw + (g == 0 ? 28 : HW - 28);
                    if (shw >= HW) shw -= HW;
                    v0 = *(const float4*)(src + 0 * HW + shw);
                    v1 = *(const float4*)(src + 1 * HW + shw);
                    v2 = *(const float4*)(src + 2 * HW + shw);
                    v3 = *(const float4*)(src + 3 * HW + shw);
                } else {
                    int h = hw / 28, w0 = hw - h * 28, base = h * 28;
                    #pragma unroll
                    for (int j = 0; j < 4; ++j) {
                        const float* row = src + j * HW + base;
                        float4 a = *(const float4*)(row + w0);
                        float4 r;
                        if (g == 2) {
                            float ex = row[(w0 + 4 < 28) ? (w0 + 4) : 0];
                            r.x = a.y; r.y = a.z; r.z = a.w; r.w = ex;
                        } else {
                            float ex = row[(w0 == 0) ? 27 : (w0 - 1)];
                            r.x = ex; r.y = a.x; r.z = a.y; r.w = a.z;
                        }
                        if (j == 0) v0 = r; else if (j == 1) v1 = r;
                        else if (j == 2) v2 = r; else v3 = r;
                    }
                }
                int m0 = mq * 4;
                { int p = (cq + 5 * (m0 + 0)) & 15;
                  *(uint2*)(&sX[(m0 + 0) * SX_STRIDE + p * 4]) = pack4(v0.x, v1.x, v2.x, v3.x); }
                { int p = (cq + 5 * (m0 + 1)) & 15;
                  *(uint2*)(&sX[(m0 + 1) * SX_STRIDE + p * 4]) = pack4(v0.y, v1.y, v2.y, v3.y); }
                { int p = (cq + 5 * (m0 + 2)) & 15;
                  *(uint2*)(&sX[(m0 + 2) * SX_STRIDE + p * 4]) = pack4(v0.z, v1.z, v2.z, v3.z); }
                { int p = (cq + 5 * (m0 + 3)) & 15;
                  *(uint2*)(&sX[(m0 + 3) * SX_STRIDE + p * 4]) = pack4(v0.w, v1.w, v2.w, v3.w); }
            }
        }
        #pragma unroll
        for (int i = 0; i < 4; ++i) {
            int e = t + i * 256;
            int ol = e >> 3, kg = (e & 7) * 8;
            const float* wr = Wf + (size_t)(o_base + ol) * CIN + k0 + kg;
            float4 a = *(const float4*)(wr);
            float4 c = *(const float4*)(wr + 4);
            uint2 lo = pack4(a.x, a.y, a.z, a.w);
            uint2 hi = pack4(c.x, c.y, c.z, c.w);
            uint4 v; v.x = lo.x; v.y = lo.y; v.z = hi.x; v.w = hi.y;
            *(uint4*)(&sW[ol * SW_STRIDE + kg]) = v;
        }
        __syncthreads();
        #pragma unroll
        for (int ks = 0; ks < BK; ks += 32) {
            short8 afrag[2];
            #pragma unroll
            for (int bo = 0; bo < 2; ++bo) {
                int row = wv * 32 + bo * 16 + m16;
                afrag[bo] = *(const short8*)(&sW[row * SW_STRIDE + ks + q * 8]);
            }
            #pragma unroll
            for (int bm = 0; bm < 7; ++bm) {
                int m = bm * 16 + m16;
                int g0 = (ks >> 2) + 2 * q;
                int p0 = (g0 + 5 * m) & 15;
                int p1 = (g0 + 1 + 5 * m) & 15;
                uint2 lo = *(const uint2*)(&sX[m * SX_STRIDE + p0 * 4]);
                uint2 hi = *(const uint2*)(&sX[m * SX_STRIDE + p1 * 4]);
                union { uint2 u2[2]; short8 s; } fb;
                fb.u2[0] = lo; fb.u2[1] = hi;
                acc[0][bm] = __builtin_amdgcn_mfma_f32_16x16x32_bf16(afrag[0], fb.s, acc[0][bm], 0, 0, 0);
                acc[1][bm] = __builtin_amdgcn_mfma_f32_16x16x32_bf16(afrag[1], fb.s, acc[1][bm], 0, 0, 0);
            }
        }
        __syncthreads();
    }
    float scl[2][4], shf[2][4];
    #pragma unroll
    for (int bo = 0; bo < 2; ++bo)
        #pragma unroll
        for (int r = 0; r < 4; ++r) {
            int o = o_base + wv * 32 + bo * 16 + q * 4 + r;
            float sc = gamma[o] * rsqrtf(rvar[o] + 1e-5f);
            scl[bo][r] = sc;
            shf[bo][r] = beta[o] - rmean[o] * sc;
        }
    float* outb = out + (size_t)b * COUT * HW;
    #pragma unroll
    for (int bo = 0; bo < 2; ++bo)
        #pragma unroll
        for (int r = 0; r < 4; ++r) {
            int o = o_base + wv * 32 + bo * 16 + q * 4 + r;
            float* orow = outb + (size_t)o * HW + hw_base + m16;
            #pragma unroll
            for (int bm = 0; bm < 7; ++bm) {
                float y = acc[bo][bm][r] * scl[bo][r] + shf[bo][r];
                y = fmaxf(y, 0.f);
                __builtin_nontemporal_store(y, orow + bm * 16);
            }
        }
}

extern "C" void kernel_launch(void* const* d_in, const int* in_sizes, int n_in,
                              void* d_out, int out_size, void* d_ws, size_t ws_size,
                              hipStream_t stream)
{
    const float* x     = (const float*)d_in[0];
    const float* W     = (const float*)d_in[1];
    const float* gamma = (const float*)d_in[2];
    const float* beta  = (const float*)d_in[3];
    const float* rmean = (const float*)d_in[4];
    const float* rvar  = (const float*)d_in[5];
    float* out = (float*)d_out;

    const size_t wb_bytes = (size_t)COUT * CIN * 2;                 // 512 KB
    if (ws_size >= wb_bytes) {
        unsigned short* Wb = (unsigned short*)d_ws;
        p0_wcvt<<<dim3(128), dim3(256), 0, stream>>>(W, Wb);
        p_fused<<<dim3(448), dim3(512), 0, stream>>>(x, Wb, gamma, beta, rmean, rvar, out);
    } else {
        dim3 grid(COUT / NT, HW / MT, BN);
        shiftconv_fallback<<<grid, 256, 0, stream>>>(x, W, gamma, beta, rmean, rvar, out);
    }
}